// Round 1
// baseline (734.432 us; speedup 1.0000x reference)
//
#include <hip/hip_runtime.h>
#include <math.h>

#define B0 32
#define C0 512
#define HW 4096
#define DC 32
#define NS 16
#define RK 32
#define L  512
#define KD 64
#define LT 128

__device__ __forceinline__ float gelu_exact(float x) {
    return 0.5f * x * (1.0f + erff(x * 0.70710678118654752f));
}
__device__ __forceinline__ float softplus_f(float x) {
    float ax = fabsf(x);
    return fmaxf(x, 0.0f) + log1pf(expf(-ax));
}

// K1: per-(b,c) avg & max over HW=4096
__global__ void pool_kernel(const float* __restrict__ x,
                            float* __restrict__ avg, float* __restrict__ mx) {
    int row = blockIdx.x;  // b*C0 + c
    const float4* xr = (const float4*)(x + (size_t)row * HW);
    int tid = threadIdx.x; // 256
    float s = 0.f, m = -INFINITY;
#pragma unroll
    for (int i = 0; i < 4; ++i) {
        float4 v = xr[tid + i * 256];
        s += v.x + v.y + v.z + v.w;
        m = fmaxf(m, fmaxf(fmaxf(v.x, v.y), fmaxf(v.z, v.w)));
    }
    for (int off = 32; off > 0; off >>= 1) {
        s += __shfl_down(s, off, 64);
        m = fmaxf(m, __shfl_down(m, off, 64));
    }
    __shared__ float ss[4], sm[4];
    int wave = tid >> 6;
    if ((tid & 63) == 0) { ss[wave] = s; sm[wave] = m; }
    __syncthreads();
    if (tid == 0) {
        s = ss[0] + ss[1] + ss[2] + ss[3];
        m = fmaxf(fmaxf(sm[0], sm[1]), fmaxf(sm[2], sm[3]));
        avg[row] = s * (1.0f / HW);
        mx[row] = m;
    }
}

// K2: h[b][d][l] = gelu(BN(avg*w0 + mx*w1))
__global__ void hgelu_kernel(const float* __restrict__ avg, const float* __restrict__ mx,
                             const float* __restrict__ w_cin,
                             const float* __restrict__ bn_g, const float* __restrict__ bn_b,
                             const float* __restrict__ bn_m, const float* __restrict__ bn_v,
                             float* __restrict__ hout) {
    int t = blockIdx.x * 256 + threadIdx.x;
    if (t >= B0 * DC * L) return;
    int l = t & (L - 1);
    int d = (t >> 9) & (DC - 1);
    int b = t >> 14;
    float a = avg[b * C0 + l], m = mx[b * C0 + l];
    float v = a * w_cin[d * 2] + m * w_cin[d * 2 + 1];
    v = (v - bn_m[d]) * rsqrtf(bn_v[d] + 1e-5f);
    v = v * bn_g[d] + bn_b[d];
    hout[t] = gelu_exact(v);
}

// K3: per (b,k,ltile): dbl -> {dts_raw, Bs, Cs}; dts proj + softplus -> delta.
// All stored in ORIGINAL l coordinates (k=1 flip handled by reverse scan in K4).
__global__ void proj_kernel(const float* __restrict__ h, const float* __restrict__ xcw,
                            const float* __restrict__ dtw, const float* __restrict__ dtb,
                            float* __restrict__ delta, float* __restrict__ Bsv,
                            float* __restrict__ Csv) {
    __shared__ float sh[DC * LT];    // 16 KB
    __shared__ float sdt[RK * LT];   // 16 KB
    __shared__ float sW[64 * DC];    // 8 KB
    __shared__ float sPW[DC * RK];   // 4 KB
    int blk = blockIdx.x;
    int lt = blk & 3;
    int k = (blk >> 2) & 1;
    int b = blk >> 3;
    int l0 = lt * LT;
    int tid = threadIdx.x; // 256
    for (int i = tid; i < DC * LT; i += 256) {
        int d = i >> 7, l = i & (LT - 1);
        sh[i] = h[((b * DC + d) << 9) + l0 + l];
    }
    for (int i = tid; i < 64 * DC; i += 256) sW[i] = xcw[k * 64 * DC + i];
    for (int i = tid; i < DC * RK; i += 256) sPW[i] = dtw[k * DC * RK + i];
    __syncthreads();
    for (int idx = tid; idx < 64 * LT; idx += 256) {
        int c = idx >> 7, l = idx & (LT - 1);
        float acc = 0.f;
#pragma unroll
        for (int d = 0; d < DC; ++d) acc += sh[d * LT + l] * sW[c * DC + d];
        if (c < RK) sdt[c * LT + l] = acc;
        else if (c < RK + NS)
            Bsv[(size_t)((((b * 2 + k) << 9) + l0 + l)) * NS + (c - RK)] = acc;
        else
            Csv[(size_t)((((b * 2 + k) << 9) + l0 + l)) * NS + (c - RK - NS)] = acc;
    }
    __syncthreads();
    for (int idx = tid; idx < DC * LT; idx += 256) {
        int d = idx >> 7, l = idx & (LT - 1);
        float acc = dtb[k * DC + d];
#pragma unroll
        for (int r = 0; r < RK; ++r) acc += sdt[r * LT + l] * sPW[d * RK + r];
        delta[((b * KD + k * DC + d) << 9) + l0 + l] = softplus_f(acc);
    }
}

// K4: selective scan. block = b*2+k; thread = (channel dl 0..31, state n 0..15).
// k=0 scans l ascending, k=1 descending (equivalent to flipped fwd scan).
__global__ void scan_kernel(const float* __restrict__ h, const float* __restrict__ delta,
                            const float* __restrict__ Bsv, const float* __restrict__ Csv,
                            const float* __restrict__ Ac_logs, const float* __restrict__ Dcs,
                            float* __restrict__ yv) {
    int blk = blockIdx.x;  // b*2+k
    int k = blk & 1, b = blk >> 1;
    int tid = threadIdx.x; // 512
    int dl = tid >> 4;
    int n = tid & 15;
    int kd = k * DC + dl;
    float A = -expf(Ac_logs[kd * NS + n]);
    float Dv = Dcs[kd];
    const float* dp = delta + ((size_t)(b * KD + kd) << 9);
    const float* up = h + ((size_t)(b * DC + dl) << 9);
    const float* Bp = Bsv + (((size_t)(b * 2 + k)) << 9) * NS;
    const float* Cp = Csv + (((size_t)(b * 2 + k)) << 9) * NS;
    float* yp = yv + ((size_t)(b * KD + kd) << 9);
    float hs = 0.f;
    for (int step = 0; step < L; ++step) {
        int l = k ? (L - 1 - step) : step;
        float de = dp[l];
        float u = up[l];
        float Bv = Bp[l * NS + n];
        float Cv = Cp[l * NS + n];
        hs = expf(de * A) * hs + de * Bv * u;
        float contrib = hs * Cv;
        contrib += __shfl_xor(contrib, 1, 16);
        contrib += __shfl_xor(contrib, 2, 16);
        contrib += __shfl_xor(contrib, 4, 16);
        contrib += __shfl_xor(contrib, 8, 16);
        if (n == 0) yp[l] = contrib + Dv * u;
    }
}

// K5: per batch: combine directions, w_cout dot, gelu, LayerNorm over L -> attn
__global__ void epi_kernel(const float* __restrict__ yv, const float* __restrict__ w_cout,
                           const float* __restrict__ ln_g, const float* __restrict__ ln_b,
                           float* __restrict__ attn) {
    int b = blockIdx.x;
    int l = threadIdx.x; // 512
    float acc = 0.f;
#pragma unroll
    for (int d = 0; d < DC; ++d) {
        float w = w_cout[d];
        acc += (yv[((b * KD + d) << 9) + l] + yv[((b * KD + DC + d) << 9) + l]) * w;
    }
    float y = gelu_exact(acc);
    float s = y, s2 = y * y;
    for (int off = 32; off > 0; off >>= 1) {
        s += __shfl_down(s, off, 64);
        s2 += __shfl_down(s2, off, 64);
    }
    __shared__ float ss[8], ss2[8];
    __shared__ float smu, srv;
    int wave = l >> 6;
    if ((l & 63) == 0) { ss[wave] = s; ss2[wave] = s2; }
    __syncthreads();
    if (l == 0) {
        float ts = 0.f, ts2 = 0.f;
#pragma unroll
        for (int i = 0; i < 8; ++i) { ts += ss[i]; ts2 += ss2[i]; }
        float mu = ts * (1.0f / L);
        float var = ts2 * (1.0f / L) - mu * mu;
        smu = mu;
        srv = rsqrtf(var + 1e-5f);
    }
    __syncthreads();
    attn[b * C0 + l] = (y - smu) * srv * ln_g[l] + ln_b[l];
}

// K6: out = x * (1 + attn[b,c]), float4
__global__ void gate_kernel(const float* __restrict__ x, const float* __restrict__ attn,
                            float* __restrict__ out) {
    size_t t = (size_t)blockIdx.x * 256 + threadIdx.x; // float4 index
    const float4* x4 = (const float4*)x;
    float4* o4 = (float4*)out;
    float4 v = x4[t];
    int bc = (int)(t >> 10); // 1024 float4 per (b,c)
    float a = 1.0f + attn[bc];
    v.x *= a; v.y *= a; v.z *= a; v.w *= a;
    o4[t] = v;
}

extern "C" void kernel_launch(void* const* d_in, const int* in_sizes, int n_in,
                              void* d_out, int out_size, void* d_ws, size_t ws_size,
                              hipStream_t stream) {
    const float* x     = (const float*)d_in[0];
    const float* xcw   = (const float*)d_in[1];
    const float* dtw   = (const float*)d_in[2];
    const float* dtb   = (const float*)d_in[3];
    const float* Aclog = (const float*)d_in[4];
    const float* Dcs   = (const float*)d_in[5];
    const float* wcin  = (const float*)d_in[6];
    const float* bng   = (const float*)d_in[7];
    const float* bnb   = (const float*)d_in[8];
    const float* bnm   = (const float*)d_in[9];
    const float* bnv   = (const float*)d_in[10];
    const float* wcout = (const float*)d_in[11];
    const float* lng   = (const float*)d_in[12];
    const float* lnb   = (const float*)d_in[13];
    float* out = (float*)d_out;

    float* ws = (float*)d_ws;
    float* avg   = ws;                 // 16384
    float* mx    = ws + 16384;         // 16384
    float* h     = ws + 32768;         // 524288
    float* delta = ws + 557056;        // 1048576
    float* Bsv   = ws + 1605632;       // 524288
    float* Csv   = ws + 2129920;       // 524288
    float* yv    = ws + 2654208;       // 1048576
    float* attn  = ws + 3702784;       // 16384

    pool_kernel<<<B0 * C0, 256, 0, stream>>>(x, avg, mx);
    hgelu_kernel<<<(B0 * DC * L) / 256, 256, 0, stream>>>(avg, mx, wcin, bng, bnb, bnm, bnv, h);
    proj_kernel<<<B0 * 2 * (L / LT), 256, 0, stream>>>(h, xcw, dtw, dtb, delta, Bsv, Csv);
    scan_kernel<<<B0 * 2, 512, 0, stream>>>(h, delta, Bsv, Csv, Aclog, Dcs, yv);
    epi_kernel<<<B0, 512, 0, stream>>>(yv, wcout, lng, lnb, attn);
    gate_kernel<<<(B0 * C0 * HW / 4) / 256, 256, 0, stream>>>(x, attn, out);
}

// Round 2
// 564.204 us; speedup vs baseline: 1.3017x; 1.3017x over previous
//
#include <hip/hip_runtime.h>
#include <math.h>

#define B0 32
#define C0 512
#define HW 4096
#define DC 32
#define NS 16
#define RK 32
#define L  512
#define KD 64
#define LT 128
#define CH 16   // chunks per (b,k)
#define CL 32   // steps per chunk

__device__ __forceinline__ float gelu_exact(float x) {
    return 0.5f * x * (1.0f + erff(x * 0.70710678118654752f));
}
__device__ __forceinline__ float softplus_f(float x) {
    float ax = fabsf(x);
    return fmaxf(x, 0.0f) + log1pf(expf(-ax));
}

// K1: per-(b,c) avg & max over HW=4096
__global__ void pool_kernel(const float* __restrict__ x,
                            float* __restrict__ avg, float* __restrict__ mx) {
    int row = blockIdx.x;  // b*C0 + c
    const float4* xr = (const float4*)(x + (size_t)row * HW);
    int tid = threadIdx.x; // 256
    float s = 0.f, m = -INFINITY;
#pragma unroll
    for (int i = 0; i < 4; ++i) {
        float4 v = xr[tid + i * 256];
        s += v.x + v.y + v.z + v.w;
        m = fmaxf(m, fmaxf(fmaxf(v.x, v.y), fmaxf(v.z, v.w)));
    }
    for (int off = 32; off > 0; off >>= 1) {
        s += __shfl_down(s, off, 64);
        m = fmaxf(m, __shfl_down(m, off, 64));
    }
    __shared__ float ss[4], sm[4];
    int wave = tid >> 6;
    if ((tid & 63) == 0) { ss[wave] = s; sm[wave] = m; }
    __syncthreads();
    if (tid == 0) {
        s = ss[0] + ss[1] + ss[2] + ss[3];
        m = fmaxf(fmaxf(sm[0], sm[1]), fmaxf(sm[2], sm[3]));
        avg[row] = s * (1.0f / HW);
        mx[row] = m;
    }
}

// K2: fused h-compute + projections. Per (b,k,ltile):
//   h = gelu(BN(avg*w0+mx*w1)) computed inline (k==0 writes h for the scans' u),
//   dbl -> {dts_raw, Bs, Cs}; dts proj + softplus -> delta.
// All stored in ORIGINAL l coordinates (k=1 flip handled by reverse scan).
__global__ void projh_kernel(const float* __restrict__ avg, const float* __restrict__ mx,
                             const float* __restrict__ w_cin,
                             const float* __restrict__ bn_g, const float* __restrict__ bn_b,
                             const float* __restrict__ bn_m, const float* __restrict__ bn_v,
                             const float* __restrict__ xcw,
                             const float* __restrict__ dtw, const float* __restrict__ dtb,
                             float* __restrict__ hout,
                             float* __restrict__ delta, float* __restrict__ Bsv,
                             float* __restrict__ Csv) {
    __shared__ float sh[DC * LT];    // 16 KB
    __shared__ float sdt[RK * LT];   // 16 KB
    __shared__ float sW[64 * DC];    // 8 KB
    __shared__ float sPW[DC * RK];   // 4 KB
    int blk = blockIdx.x;
    int lt = blk & 3;
    int k = (blk >> 2) & 1;
    int b = blk >> 3;
    int l0 = lt * LT;
    int tid = threadIdx.x; // 256
    for (int i = tid; i < DC * LT; i += 256) {
        int d = i >> 7, l = i & (LT - 1);
        int gl = l0 + l;
        float a = avg[b * C0 + gl], m = mx[b * C0 + gl];
        float v = a * w_cin[d * 2] + m * w_cin[d * 2 + 1];
        v = (v - bn_m[d]) * rsqrtf(bn_v[d] + 1e-5f);
        v = v * bn_g[d] + bn_b[d];
        v = gelu_exact(v);
        sh[i] = v;
        if (k == 0) hout[((b * DC + d) << 9) + gl] = v;
    }
    for (int i = tid; i < 64 * DC; i += 256) sW[i] = xcw[k * 64 * DC + i];
    for (int i = tid; i < DC * RK; i += 256) sPW[i] = dtw[k * DC * RK + i];
    __syncthreads();
    for (int idx = tid; idx < 64 * LT; idx += 256) {
        int c = idx >> 7, l = idx & (LT - 1);
        float acc = 0.f;
#pragma unroll
        for (int d = 0; d < DC; ++d) acc += sh[d * LT + l] * sW[c * DC + d];
        if (c < RK) sdt[c * LT + l] = acc;
        else if (c < RK + NS)
            Bsv[(size_t)((((b * 2 + k) << 9) + l0 + l)) * NS + (c - RK)] = acc;
        else
            Csv[(size_t)((((b * 2 + k) << 9) + l0 + l)) * NS + (c - RK - NS)] = acc;
    }
    __syncthreads();
    for (int idx = tid; idx < DC * LT; idx += 256) {
        int d = idx >> 7, l = idx & (LT - 1);
        float acc = dtb[k * DC + d];
#pragma unroll
        for (int r = 0; r < RK; ++r) acc += sdt[r * LT + l] * sPW[d * RK + r];
        delta[((b * KD + k * DC + d) << 9) + l0 + l] = softplus_f(acc);
    }
}

// K3: scan phase A — per (b,k,chunk): each thread (d,n) scans its 32-step
// chunk with zero carry; stores chunk-end state and sum of delta
// (chunk product of exp(de*A) == exp(A*sum_de)).
__global__ void scanA_kernel(const float* __restrict__ h, const float* __restrict__ delta,
                             const float* __restrict__ Bsv,
                             const float* __restrict__ Ac_logs,
                             float* __restrict__ Sde, float* __restrict__ hend) {
    int blk = blockIdx.x;          // ((b*2+k)*CH + c)
    int c = blk & (CH - 1);
    int k = (blk >> 4) & 1;
    int b = blk >> 5;
    int tid = threadIdx.x;         // 512
    int d = tid >> 4;
    int n = tid & 15;
    int kd = k * DC + d;
    float A = -expf(Ac_logs[kd * NS + n]);
    const float* dp = delta + ((size_t)(b * KD + kd) << 9);
    const float* up = h + ((size_t)(b * DC + d) << 9);
    const float* Bp = Bsv + (((size_t)(b * 2 + k)) << 9) * NS;
    int s0 = c * CL;
    float hs = 0.f, sde = 0.f;
#pragma unroll 4
    for (int sl = 0; sl < CL; ++sl) {
        int s = s0 + sl;
        int l = k ? (L - 1 - s) : s;
        float de = dp[l];
        float u = up[l];
        float Bv = Bp[l * NS + n];
        hs = expf(de * A) * hs + de * Bv * u;
        sde += de;
    }
    hend[((size_t)blk * DC + d) * NS + n] = hs;
    if (n == 0) Sde[blk * DC + d] = sde;
}

// K4: scan phase B — compose carry from chunk summaries, re-run the 32 steps,
// reduce over n (shfl) and over d (LDS, w_cout-weighted), atomicAdd into ybl[b,l].
__global__ void scanB_kernel(const float* __restrict__ h, const float* __restrict__ delta,
                             const float* __restrict__ Bsv, const float* __restrict__ Csv,
                             const float* __restrict__ Ac_logs, const float* __restrict__ Dcs,
                             const float* __restrict__ w_cout,
                             const float* __restrict__ Sde, const float* __restrict__ hend,
                             float* __restrict__ ybl) {
    __shared__ float red[DC][CL + 1];
    int blk = blockIdx.x;
    int c = blk & (CH - 1);
    int k = (blk >> 4) & 1;
    int b = blk >> 5;
    int tid = threadIdx.x;         // 512
    int d = tid >> 4;
    int n = tid & 15;
    int kd = k * DC + d;
    float A = -expf(Ac_logs[kd * NS + n]);
    float w = w_cout[d];
    float Dv = Dcs[kd];
    // carry composition over earlier chunks
    int base = (b * 2 + k) * CH;
    float carry = 0.f;
    for (int j = 0; j < c; ++j) {
        float sde = Sde[(base + j) * DC + d];
        float he = hend[((size_t)(base + j) * DC + d) * NS + n];
        carry = expf(A * sde) * carry + he;
    }
    const float* dp = delta + ((size_t)(b * KD + kd) << 9);
    const float* up = h + ((size_t)(b * DC + d) << 9);
    const float* Bp = Bsv + (((size_t)(b * 2 + k)) << 9) * NS;
    const float* Cp = Csv + (((size_t)(b * 2 + k)) << 9) * NS;
    int s0 = c * CL;
    float hs = carry;
#pragma unroll 4
    for (int sl = 0; sl < CL; ++sl) {
        int s = s0 + sl;
        int l = k ? (L - 1 - s) : s;
        float de = dp[l];
        float u = up[l];
        float Bv = Bp[l * NS + n];
        float Cv = Cp[l * NS + n];
        hs = expf(de * A) * hs + de * Bv * u;
        float contrib = hs * Cv;
        contrib += __shfl_xor(contrib, 1, 16);
        contrib += __shfl_xor(contrib, 2, 16);
        contrib += __shfl_xor(contrib, 4, 16);
        contrib += __shfl_xor(contrib, 8, 16);
        if (n == 0) red[d][sl] = w * (contrib + Dv * u);
    }
    __syncthreads();
    if (tid < CL) {
        int sl = tid;
        float acc = 0.f;
#pragma unroll
        for (int dd = 0; dd < DC; ++dd) acc += red[dd][sl];
        int s = s0 + sl;
        int l = k ? (L - 1 - s) : s;
        atomicAdd(&ybl[b * L + l], acc);
    }
}

// K5: per batch: gelu + LayerNorm over L -> attn
__global__ void epi_kernel(const float* __restrict__ ybl,
                           const float* __restrict__ ln_g, const float* __restrict__ ln_b,
                           float* __restrict__ attn) {
    int b = blockIdx.x;
    int l = threadIdx.x; // 512
    float y = gelu_exact(ybl[b * L + l]);
    float s = y, s2 = y * y;
    for (int off = 32; off > 0; off >>= 1) {
        s += __shfl_down(s, off, 64);
        s2 += __shfl_down(s2, off, 64);
    }
    __shared__ float ss[8], ss2[8];
    __shared__ float smu, srv;
    int wave = l >> 6;
    if ((l & 63) == 0) { ss[wave] = s; ss2[wave] = s2; }
    __syncthreads();
    if (l == 0) {
        float ts = 0.f, ts2 = 0.f;
#pragma unroll
        for (int i = 0; i < 8; ++i) { ts += ss[i]; ts2 += ss2[i]; }
        float mu = ts * (1.0f / L);
        float var = ts2 * (1.0f / L) - mu * mu;
        smu = mu;
        srv = rsqrtf(var + 1e-5f);
    }
    __syncthreads();
    attn[b * C0 + l] = (y - smu) * srv * ln_g[l] + ln_b[l];
}

// K6: out = x * (1 + attn[b,c]), float4
__global__ void gate_kernel(const float* __restrict__ x, const float* __restrict__ attn,
                            float* __restrict__ out) {
    size_t t = (size_t)blockIdx.x * 256 + threadIdx.x; // float4 index
    const float4* x4 = (const float4*)x;
    float4* o4 = (float4*)out;
    float4 v = x4[t];
    int bc = (int)(t >> 10); // 1024 float4 per (b,c)
    float a = 1.0f + attn[bc];
    v.x *= a; v.y *= a; v.z *= a; v.w *= a;
    o4[t] = v;
}

extern "C" void kernel_launch(void* const* d_in, const int* in_sizes, int n_in,
                              void* d_out, int out_size, void* d_ws, size_t ws_size,
                              hipStream_t stream) {
    const float* x     = (const float*)d_in[0];
    const float* xcw   = (const float*)d_in[1];
    const float* dtw   = (const float*)d_in[2];
    const float* dtb   = (const float*)d_in[3];
    const float* Aclog = (const float*)d_in[4];
    const float* Dcs   = (const float*)d_in[5];
    const float* wcin  = (const float*)d_in[6];
    const float* bng   = (const float*)d_in[7];
    const float* bnb   = (const float*)d_in[8];
    const float* bnm   = (const float*)d_in[9];
    const float* bnv   = (const float*)d_in[10];
    const float* wcout = (const float*)d_in[11];
    const float* lng   = (const float*)d_in[12];
    const float* lnb   = (const float*)d_in[13];
    float* out = (float*)d_out;

    float* ws = (float*)d_ws;
    float* avg   = ws;                 // 16384
    float* mx    = ws + 16384;         // 16384
    float* h     = ws + 32768;         // 524288
    float* delta = ws + 557056;        // 1048576
    float* Bsv   = ws + 1605632;       // 524288
    float* Csv   = ws + 2129920;       // 524288
    float* Sde   = ws + 2654208;       // 32768  (B0*2*CH*DC)
    float* hend  = ws + 2686976;       // 524288 (B0*2*CH*DC*NS)
    float* ybl   = ws + 3211264;       // 16384
    float* attn  = ws + 3227648;       // 16384

    pool_kernel<<<B0 * C0, 256, 0, stream>>>(x, avg, mx);
    projh_kernel<<<B0 * 2 * (L / LT), 256, 0, stream>>>(avg, mx, wcin, bng, bnb, bnm, bnv,
                                                        xcw, dtw, dtb, h, delta, Bsv, Csv);
    hipMemsetAsync(ybl, 0, (size_t)B0 * L * sizeof(float), stream);
    scanA_kernel<<<B0 * 2 * CH, 512, 0, stream>>>(h, delta, Bsv, Aclog, Sde, hend);
    scanB_kernel<<<B0 * 2 * CH, 512, 0, stream>>>(h, delta, Bsv, Csv, Aclog, Dcs, wcout,
                                                  Sde, hend, ybl);
    epi_kernel<<<B0, 512, 0, stream>>>(ybl, lng, lnb, attn);
    gate_kernel<<<(B0 * C0 * HW / 4) / 256, 256, 0, stream>>>(x, attn, out);
}